// Round 3
// baseline (263.681 us; speedup 1.0000x reference)
//
#include <hip/hip_runtime.h>

#define NCC_EPS 1.1920929e-07f

// ---------------------------------------------------------------------------
// Fused single-scale NCC: per block = one 16x16 (H,W) tile x one D-chunk.
// March along D keeping a WIN-deep register ring of HW-box-filtered slices
// (5 channels: I, J, I^2, J^2, I*J) and running D-window sums.
//
// LDS layouts are bank-conflict-engineered:
//   staging: 24 data cols in rows of stride SW=40 floats (40%32==8 ->
//            4 rows/wave land on distinct bank octets, max 2-way = free)
//   wb:      row stride 24 (24%32: offsets {0,24,16,8} -> 2-way = free)
// Staging is float4 (global dwordx4 -> ds_write_b128), W-pass is pair-shared
// (2 output cols per thread from 5 ds_read_b64 taps per array).
// ---------------------------------------------------------------------------
template<int WIN>
__global__ __launch_bounds__(256)
void ncc_scale_kernel(const float* __restrict__ I, const float* __restrict__ J,
                      int D, int H, int W,
                      int tilesH, int tilesW, int chunksD, int chunkLen,
                      double* __restrict__ acc)
{
    constexpr int RAD  = WIN / 2;
    constexpr int SRAD = 4;                 // staging halo (uniform, alignment)
    constexpr int OFF  = SRAD - RAD;        // compute offset into staged patch
    constexpr int TH = 16, TW = 16;
    constexpr int SROWS = TH + 2 * SRAD;    // 24 staged data rows
    constexpr int SCOLS = TW + 2 * SRAD;    // 24 staged data cols
    constexpr int SW = 40;                  // LDS staging row stride (floats)
    constexpr int WROWS = TH + 2 * RAD;     // wb rows (H extent incl. halo)
    constexpr int WSTR  = 24;               // wb row stride (floats)
    constexpr int NCH4  = SCOLS / 4;        // 6 float4 chunks per staged row
    constexpr int NSTG  = SROWS * NCH4;     // 144 staging chunks per array
    constexpr int S0 = OFF / 2;             // first b64 tap chunk
    constexpr int S1 = (OFF + WIN) / 2;     // last  b64 tap chunk (inclusive)
    constexpr float invV = 1.0f / (float)(WIN * WIN * WIN);

    __shared__ float sI[SROWS * SW];
    __shared__ float sJ[SROWS * SW];
    __shared__ float wb[5][WROWS * WSTR];
    __shared__ float red[4];

    int bid = blockIdx.x;
    int tw = bid % tilesW; bid /= tilesW;
    int th = bid % tilesH; bid /= tilesH;
    int cd = bid % chunksD; bid /= chunksD;
    int b  = bid;

    const int h0 = th * TH, w0 = tw * TW;
    const int z0 = cd * chunkLen;
    const int z1 = min(z0 + chunkLen, D);

    // block-uniform: whole staged patch (halo 4) in bounds?
    const bool intHW = (h0 >= SRAD) && (h0 + TH + SRAD <= H) &&
                       (w0 >= SRAD) && (w0 + TW + SRAD <= W);

    const size_t plane = (size_t)H * W;
    const float* Ib = I + (size_t)b * D * plane;
    const float* Jb = J + (size_t)b * D * plane;

    const int t  = threadIdx.x;
    const int hh = t >> 4, ww = t & 15;       // owned output point in tile
    const int gh = h0 + hh, gw = w0 + ww;
    const bool valid = (gh < H) && (gw < W);

    // W-pass mapping: row r, column pair c2
    const int wr = t >> 3;
    const int wc2 = (t & 7) << 1;
    const bool wact = t < WROWS * 8;

    // staging chunk mapping
    const int ir = t / NCH4, ik = t - ir * NCH4;              // I: t < NSTG
    const int jt = t - (256 - NSTG);
    const int jr = jt / NCH4, jk = jt - jr * NCH4;            // J: t >= 256-NSTG

    float ring[WIN][5];
    float rs[5];
    #pragma unroll
    for (int s = 0; s < WIN; ++s)
        #pragma unroll
        for (int c = 0; c < 5; ++c) ring[s][c] = 0.f;
    #pragma unroll
    for (int c = 0; c < 5; ++c) rs[c] = 0.f;

    float ccsum = 0.f;

    const int zend = z1 + RAD;
    for (int zb = z0 - RAD; zb < zend; zb += WIN) {
        #pragma unroll
        for (int ph = 0; ph < WIN; ++ph) {
            const int z = zb + ph;                 // uniform across block
            if (z < zend) {
                const bool zin = (z >= 0) && (z < D);   // uniform
                float n0 = 0, n1 = 0, n2 = 0, n3 = 0, n4 = 0;
                if (zin) {
                    // ---- stage 24x24 patch (zero-padded at edges) ----
                    if (intHW) {
                        const float* base = Ib + (size_t)z * plane
                                          + (size_t)(h0 - SRAD) * W + (w0 - SRAD);
                        const float* baseJ = Jb + (size_t)z * plane
                                           + (size_t)(h0 - SRAD) * W + (w0 - SRAD);
                        if (t < NSTG) {
                            float4 v = *reinterpret_cast<const float4*>(base + (size_t)ir * W + 4 * ik);
                            *reinterpret_cast<float4*>(&sI[ir * SW + 4 * ik]) = v;
                        }
                        if (t >= 256 - NSTG) {
                            float4 v = *reinterpret_cast<const float4*>(baseJ + (size_t)jr * W + 4 * jk);
                            *reinterpret_cast<float4*>(&sJ[jr * SW + 4 * jk]) = v;
                        }
                    } else {
                        #pragma unroll
                        for (int k = 0; k < (SROWS * SCOLS + 255) / 256; ++k) {
                            int idx = t + k * 256;
                            if (idx < SROWS * SCOLS) {
                                int r = idx / SCOLS, c = idx - r * SCOLS;
                                int gh2 = h0 + r - SRAD, gw2 = w0 + c - SRAD;
                                float vi = 0.f, vj = 0.f;
                                if (gh2 >= 0 && gh2 < H && gw2 >= 0 && gw2 < W) {
                                    size_t off = (size_t)z * plane + (size_t)gh2 * W + gw2;
                                    vi = Ib[off];
                                    vj = Jb[off];
                                }
                                sI[r * SW + c] = vi;
                                sJ[r * SW + c] = vj;
                            }
                        }
                    }
                    __syncthreads();
                    // ---- W filter: 2 adjacent output cols per thread ----
                    if (wact) {
                        const int sbase = (wr + OFF) * SW + wc2;
                        float fi[12], fj[12];
                        #pragma unroll
                        for (int s = S0; s <= S1; ++s) {
                            float2 a = *reinterpret_cast<const float2*>(&sI[sbase + 2 * s]);
                            fi[2 * s] = a.x; fi[2 * s + 1] = a.y;
                            float2 c2v = *reinterpret_cast<const float2*>(&sJ[sbase + 2 * s]);
                            fj[2 * s] = c2v.x; fj[2 * s + 1] = c2v.y;
                        }
                        float m0 = 0, m1 = 0, m2 = 0, m3 = 0, m4 = 0;
                        #pragma unroll
                        for (int dw = 0; dw < WIN; ++dw) {
                            float vi = fi[OFF + dw], vj = fj[OFF + dw];
                            m0 += vi; m1 += vj;
                            m2 += vi * vi; m3 += vj * vj; m4 += vi * vj;
                        }
                        const float ai = fi[OFF], aj = fj[OFF];
                        const float bi = fi[OFF + WIN], bj = fj[OFF + WIN];
                        const float p0 = m0 - ai + bi;
                        const float p1 = m1 - aj + bj;
                        const float p2 = m2 - ai * ai + bi * bi;
                        const float p3 = m3 - aj * aj + bj * bj;
                        const float p4 = m4 - ai * aj + bi * bj;
                        const int wob = wr * WSTR + wc2;
                        *reinterpret_cast<float2*>(&wb[0][wob]) = make_float2(m0, p0);
                        *reinterpret_cast<float2*>(&wb[1][wob]) = make_float2(m1, p1);
                        *reinterpret_cast<float2*>(&wb[2][wob]) = make_float2(m2, p2);
                        *reinterpret_cast<float2*>(&wb[3][wob]) = make_float2(m3, p3);
                        *reinterpret_cast<float2*>(&wb[4][wob]) = make_float2(m4, p4);
                    }
                    __syncthreads();
                    // ---- H filter at this thread's point ----
                    #pragma unroll
                    for (int dh = 0; dh < WIN; ++dh) {
                        const int base = (hh + dh) * WSTR + ww;
                        n0 += wb[0][base]; n1 += wb[1][base]; n2 += wb[2][base];
                        n3 += wb[3][base]; n4 += wb[4][base];
                    }
                }
                // ---- ring update (zeros for out-of-range slices) ----
                rs[0] += n0 - ring[ph][0]; ring[ph][0] = n0;
                rs[1] += n1 - ring[ph][1]; ring[ph][1] = n1;
                rs[2] += n2 - ring[ph][2]; ring[ph][2] = n2;
                rs[3] += n3 - ring[ph][3]; ring[ph][3] = n3;
                rs[4] += n4 - ring[ph][4]; ring[ph][4] = n4;

                // ---- emit cc for output slice zo = z - RAD ----
                const int zo = z - RAD;
                if (valid && zo >= z0) {
                    float muI = rs[0] * invV;
                    float muJ = rs[1] * invV;
                    float sII = rs[2] * invV - muI * muI;
                    float sJJ = rs[3] * invV - muJ * muJ;
                    float s12 = rs[4] * invV - muI * muJ;
                    float cc = (s12 * s12) / fmaxf(sII * sJJ, NCC_EPS);
                    ccsum += cc;
                }
            }
        }
    }

    // ---- block reduction -> global double accumulator ----
    for (int off = 32; off > 0; off >>= 1)
        ccsum += __shfl_down(ccsum, off);
    const int wid = t >> 6, lane = t & 63;
    if (lane == 0) red[wid] = ccsum;
    __syncthreads();
    if (t == 0) {
        float s = red[0] + red[1] + red[2] + red[3];
        atomicAdd(acc, (double)s);
    }
}

// ---------------------------------------------------------------------------
// avg_pool3d, k=3, stride=2, pad=1, count_include_pad=False.
// One launch handles both I and J (idx >= total -> J).
// ---------------------------------------------------------------------------
__global__ void pool_kernel2(const float* __restrict__ inA, const float* __restrict__ inB,
                             float* __restrict__ outA, float* __restrict__ outB,
                             int D, int H, int W, int oD, int oH, int oW, int total)
{
    int idx0 = blockIdx.x * 256 + threadIdx.x;
    if (idx0 >= 2 * total) return;
    const bool isB = idx0 >= total;
    int idx = isB ? idx0 - total : idx0;
    const float* in = isB ? inB : inA;
    float* out = isB ? outB : outA;

    int ow = idx % oW; int tmp = idx / oW;
    int oh = tmp % oH; tmp /= oH;
    int od = tmp % oD; int b = tmp / oD;

    int d0 = 2 * od - 1, h0 = 2 * oh - 1, w0 = 2 * ow - 1;
    int dlo = max(d0, 0), dhi = min(d0 + 3, D);
    int hlo = max(h0, 0), hhi = min(h0 + 3, H);
    int wlo = max(w0, 0), whi = min(w0 + 3, W);

    const float* ib = in + (size_t)b * D * H * W;
    float s = 0.f;
    for (int d = dlo; d < dhi; ++d)
        for (int h = hlo; h < hhi; ++h)
            for (int w = wlo; w < whi; ++w)
                s += ib[((size_t)d * H + h) * W + w];
    int cnt = (dhi - dlo) * (hhi - hlo) * (whi - wlo);
    out[idx] = s / (float)cnt;
}

__global__ void finalize_kernel(const double* __restrict__ acc, float* __restrict__ out)
{
    double m = acc[0] / 9830400.0 + acc[1] / 1228800.0 + acc[2] / 153600.0;
    out[0] = (float)(-m / 3.0);
}

extern "C" void kernel_launch(void* const* d_in, const int* in_sizes, int n_in,
                              void* d_out, int out_size, void* d_ws, size_t ws_size,
                              hipStream_t stream)
{
    const float* I0 = (const float*)d_in[0];
    const float* J0 = (const float*)d_in[1];
    float* out = (float*)d_out;

    char* ws = (char*)d_ws;
    double* acc = (double*)ws;                         // 3 doubles
    float* I1 = (float*)(ws + 256);
    float* J1 = I1 + (size_t)2 * 80 * 96 * 80;
    float* I2 = J1 + (size_t)2 * 80 * 96 * 80;
    float* J2 = I2 + (size_t)2 * 40 * 48 * 40;

    hipMemsetAsync(acc, 0, 3 * sizeof(double), stream);

    // ---- scale 0: 160x192x160, win=9 ----
    {
        int H = 192, W = 160, D = 160;
        int tilesH = 12, tilesW = 10;
        int chunksD = 5, chunkLen = 32;                 // 1200 blocks
        int blocks = 2 * tilesH * tilesW * chunksD;
        ncc_scale_kernel<9><<<blocks, 256, 0, stream>>>(I0, J0, D, H, W,
                                                        tilesH, tilesW, chunksD, chunkLen,
                                                        acc + 0);
    }
    // ---- pool level 0 -> 1 (I and J in one launch) ----
    {
        int total = 2 * 80 * 96 * 80;
        int blocks = (2 * total + 255) / 256;
        pool_kernel2<<<blocks, 256, 0, stream>>>(I0, J0, I1, J1,
                                                 160, 192, 160, 80, 96, 80, total);
    }
    // ---- scale 1: 80x96x80, win=7 ----
    {
        int H = 96, W = 80, D = 80;
        int tilesH = 6, tilesW = 5;
        int chunksD = 6, chunkLen = 14;                 // 360 blocks
        int blocks = 2 * tilesH * tilesW * chunksD;
        ncc_scale_kernel<7><<<blocks, 256, 0, stream>>>(I1, J1, D, H, W,
                                                        tilesH, tilesW, chunksD, chunkLen,
                                                        acc + 1);
    }
    // ---- pool level 1 -> 2 ----
    {
        int total = 2 * 40 * 48 * 40;
        int blocks = (2 * total + 255) / 256;
        pool_kernel2<<<blocks, 256, 0, stream>>>(I1, J1, I2, J2,
                                                 80, 96, 80, 40, 48, 40, total);
    }
    // ---- scale 2: 40x48x40, win=5 ----
    {
        int H = 48, W = 40, D = 40;
        int tilesH = 3, tilesW = 3;
        int chunksD = 10, chunkLen = 4;                 // 180 blocks
        int blocks = 2 * tilesH * tilesW * chunksD;
        ncc_scale_kernel<5><<<blocks, 256, 0, stream>>>(I2, J2, D, H, W,
                                                        tilesH, tilesW, chunksD, chunkLen,
                                                        acc + 2);
    }

    finalize_kernel<<<1, 1, 0, stream>>>(acc, out);
}

// Round 4
// 235.030 us; speedup vs baseline: 1.1219x; 1.1219x over previous
//
#include <hip/hip_runtime.h>

#define NCC_EPS 1.1920929e-07f

// ---------------------------------------------------------------------------
// Fused single-scale NCC: per block = one 16x16 (H,W) tile x one D-chunk.
// March along D keeping a WIN-deep register ring of HW-box-filtered slices
// (5 channels: I, J, I^2, J^2, I*J) and running D-window sums.
//
// LDS bank design (all verified per-wave, 32 banks x 4B, wave64):
//   sIJ  : interleaved {I,J}, row stride 72 floats (72%32==8). W-pass b64 taps
//          from 4 rows x 16 cols/wave: start banks (8r+2c)%32 -> exactly
//          4 words/bank = b64 floor (conflict-free).
//   wb01/wb23 : {ch0,ch1}/{ch2,ch3} float2, row stride 40 (40%32==8): b64
//          reads/writes uniform 4 words/bank (free).
//   wb4  : ch4 scalar, row stride 24 (24%32==24): rows map {0,24,16,8} ->
//          2 lanes/bank for b32 (free).
// Staging: interior blocks do float4 global loads (16B aligned at all scales)
// and 4x ds_write_b64 of interleaved pairs.
// ---------------------------------------------------------------------------
template<int WIN>
__global__ __launch_bounds__(256)
void ncc_scale_kernel(const float* __restrict__ I, const float* __restrict__ J,
                      int D, int H, int W,
                      int tilesH, int tilesW, int chunksD, int chunkLen,
                      double* __restrict__ acc)
{
    constexpr int RAD  = WIN / 2;
    constexpr int SRAD = 4;                 // staging halo (uniform)
    constexpr int OFF  = SRAD - RAD;        // compute offset into staged patch
    constexpr int TH = 16, TW = 16;
    constexpr int SROWS = TH + 2 * SRAD;    // 24 staged rows
    constexpr int SCOLS = TW + 2 * SRAD;    // 24 staged cols
    constexpr int SS   = 72;                // sIJ row stride (floats), 48 used
    constexpr int WROWS = TH + 2 * RAD;     // wb rows (H extent incl. halo)
    constexpr int PSTR = 40;                // wb01/wb23 row stride (floats)
    constexpr int QSTR = 24;                // wb4 row stride (floats)
    constexpr int NCH4 = SCOLS / 4;         // 6 float4 chunks per staged row
    constexpr int NSTG = SROWS * NCH4;      // 144 staging units
    constexpr float invV = 1.0f / (float)(WIN * WIN * WIN);

    __shared__ __align__(16) float sIJ[SROWS * SS];
    __shared__ __align__(16) float wb01[WROWS * PSTR];
    __shared__ __align__(16) float wb23[WROWS * PSTR];
    __shared__ __align__(16) float wb4[WROWS * QSTR];
    __shared__ float red[4];

    int bid = blockIdx.x;
    int tw = bid % tilesW; bid /= tilesW;
    int th = bid % tilesH; bid /= tilesH;
    int cd = bid % chunksD; bid /= chunksD;
    int b  = bid;

    const int h0 = th * TH, w0 = tw * TW;
    const int z0 = cd * chunkLen;
    const int z1 = min(z0 + chunkLen, D);

    const bool intHW = (h0 >= SRAD) && (h0 + TH + SRAD <= H) &&
                       (w0 >= SRAD) && (w0 + TW + SRAD <= W);

    const size_t plane = (size_t)H * W;
    const float* Ib = I + (size_t)b * D * plane;
    const float* Jb = J + (size_t)b * D * plane;

    const int t  = threadIdx.x;
    const int hh = t >> 4, ww = t & 15;       // owned output point in tile
    const int gh = h0 + hh, gw = w0 + ww;
    const bool valid = (gh < H) && (gw < W);

    // staging unit mapping (t < NSTG): row ir, float4-chunk ik
    const int ir = t / NCH4, ik = t - ir * NCH4;

    float ring[WIN][5];
    float rs[5];
    #pragma unroll
    for (int s = 0; s < WIN; ++s)
        #pragma unroll
        for (int c = 0; c < 5; ++c) ring[s][c] = 0.f;
    #pragma unroll
    for (int c = 0; c < 5; ++c) rs[c] = 0.f;

    float ccsum = 0.f;

    const int zend = z1 + RAD;
    for (int zb = z0 - RAD; zb < zend; zb += WIN) {
        #pragma unroll
        for (int ph = 0; ph < WIN; ++ph) {
            const int z = zb + ph;                 // uniform across block
            if (z < zend) {
                const bool zin = (z >= 0) && (z < D);   // uniform
                float n0 = 0, n1 = 0, n2 = 0, n3 = 0, n4 = 0;
                if (zin) {
                    // ---- stage 24x24 interleaved {I,J} patch ----
                    if (intHW) {
                        if (t < NSTG) {
                            const size_t goff = (size_t)z * plane
                                              + (size_t)(h0 - SRAD + ir) * W
                                              + (w0 - SRAD + 4 * ik);
                            float4 vi = *reinterpret_cast<const float4*>(Ib + goff);
                            float4 vj = *reinterpret_cast<const float4*>(Jb + goff);
                            const int wb_ = ir * SS + 8 * ik;
                            *reinterpret_cast<float2*>(&sIJ[wb_ + 0]) = make_float2(vi.x, vj.x);
                            *reinterpret_cast<float2*>(&sIJ[wb_ + 2]) = make_float2(vi.y, vj.y);
                            *reinterpret_cast<float2*>(&sIJ[wb_ + 4]) = make_float2(vi.z, vj.z);
                            *reinterpret_cast<float2*>(&sIJ[wb_ + 6]) = make_float2(vi.w, vj.w);
                        }
                    } else {
                        #pragma unroll
                        for (int k = 0; k < (SROWS * SCOLS + 255) / 256; ++k) {
                            int idx = t + k * 256;
                            if (idx < SROWS * SCOLS) {
                                int r = idx / SCOLS, c = idx - r * SCOLS;
                                int gh2 = h0 + r - SRAD, gw2 = w0 + c - SRAD;
                                float vi = 0.f, vj = 0.f;
                                if (gh2 >= 0 && gh2 < H && gw2 >= 0 && gw2 < W) {
                                    size_t off = (size_t)z * plane + (size_t)gh2 * W + gw2;
                                    vi = Ib[off];
                                    vj = Jb[off];
                                }
                                *reinterpret_cast<float2*>(&sIJ[r * SS + 2 * c]) = make_float2(vi, vj);
                            }
                        }
                    }
                    __syncthreads();
                    // ---- W filter: WROWS x 16 points, 9 b64 taps each ----
                    #pragma unroll
                    for (int k = 0; k < (WROWS * 16 + 255) / 256; ++k) {
                        int idx = t + k * 256;
                        if (idx < WROWS * 16) {
                            int r = idx >> 4, c = idx & 15;
                            const int sbase = (r + OFF) * SS + 2 * (c + OFF);
                            float m0 = 0, m1 = 0, m2 = 0, m3 = 0, m4 = 0;
                            #pragma unroll
                            for (int dw = 0; dw < WIN; ++dw) {
                                float2 v = *reinterpret_cast<const float2*>(&sIJ[sbase + 2 * dw]);
                                m0 += v.x; m1 += v.y;
                                m2 = fmaf(v.x, v.x, m2);
                                m3 = fmaf(v.y, v.y, m3);
                                m4 = fmaf(v.x, v.y, m4);
                            }
                            const int p = r * PSTR + 2 * c;
                            *reinterpret_cast<float2*>(&wb01[p]) = make_float2(m0, m1);
                            *reinterpret_cast<float2*>(&wb23[p]) = make_float2(m2, m3);
                            wb4[r * QSTR + c] = m4;
                        }
                    }
                    __syncthreads();
                    // ---- H filter at this thread's point ----
                    #pragma unroll
                    for (int dh = 0; dh < WIN; ++dh) {
                        const int p = (hh + dh) * PSTR + 2 * ww;
                        float2 a = *reinterpret_cast<const float2*>(&wb01[p]);
                        float2 c2 = *reinterpret_cast<const float2*>(&wb23[p]);
                        n0 += a.x; n1 += a.y; n2 += c2.x; n3 += c2.y;
                        n4 += wb4[(hh + dh) * QSTR + ww];
                    }
                }
                // ---- ring update (zeros for out-of-range slices) ----
                rs[0] += n0 - ring[ph][0]; ring[ph][0] = n0;
                rs[1] += n1 - ring[ph][1]; ring[ph][1] = n1;
                rs[2] += n2 - ring[ph][2]; ring[ph][2] = n2;
                rs[3] += n3 - ring[ph][3]; ring[ph][3] = n3;
                rs[4] += n4 - ring[ph][4]; ring[ph][4] = n4;

                // ---- emit cc for output slice zo = z - RAD ----
                const int zo = z - RAD;
                if (valid && zo >= z0) {
                    float muI = rs[0] * invV;
                    float muJ = rs[1] * invV;
                    float sII = rs[2] * invV - muI * muI;
                    float sJJ = rs[3] * invV - muJ * muJ;
                    float s12 = rs[4] * invV - muI * muJ;
                    float cc = (s12 * s12) / fmaxf(sII * sJJ, NCC_EPS);
                    ccsum += cc;
                }
            }
        }
    }

    // ---- block reduction -> global double accumulator ----
    for (int off = 32; off > 0; off >>= 1)
        ccsum += __shfl_down(ccsum, off);
    const int wid = t >> 6, lane = t & 63;
    if (lane == 0) red[wid] = ccsum;
    __syncthreads();
    if (t == 0) {
        float s = red[0] + red[1] + red[2] + red[3];
        atomicAdd(acc, (double)s);
    }
}

// ---------------------------------------------------------------------------
// avg_pool3d, k=3, stride=2, pad=1, count_include_pad=False.
// One launch handles both I and J (idx >= total -> J).
// ---------------------------------------------------------------------------
__global__ void pool_kernel2(const float* __restrict__ inA, const float* __restrict__ inB,
                             float* __restrict__ outA, float* __restrict__ outB,
                             int D, int H, int W, int oD, int oH, int oW, int total)
{
    int idx0 = blockIdx.x * 256 + threadIdx.x;
    if (idx0 >= 2 * total) return;
    const bool isB = idx0 >= total;
    int idx = isB ? idx0 - total : idx0;
    const float* in = isB ? inB : inA;
    float* out = isB ? outB : outA;

    int ow = idx % oW; int tmp = idx / oW;
    int oh = tmp % oH; tmp /= oH;
    int od = tmp % oD; int b = tmp / oD;

    int d0 = 2 * od - 1, h0 = 2 * oh - 1, w0 = 2 * ow - 1;
    int dlo = max(d0, 0), dhi = min(d0 + 3, D);
    int hlo = max(h0, 0), hhi = min(h0 + 3, H);
    int wlo = max(w0, 0), whi = min(w0 + 3, W);

    const float* ib = in + (size_t)b * D * H * W;
    float s = 0.f;
    for (int d = dlo; d < dhi; ++d)
        for (int h = hlo; h < hhi; ++h)
            for (int w = wlo; w < whi; ++w)
                s += ib[((size_t)d * H + h) * W + w];
    int cnt = (dhi - dlo) * (hhi - hlo) * (whi - wlo);
    out[idx] = s / (float)cnt;
}

__global__ void finalize_kernel(const double* __restrict__ acc, float* __restrict__ out)
{
    double m = acc[0] / 9830400.0 + acc[1] / 1228800.0 + acc[2] / 153600.0;
    out[0] = (float)(-m / 3.0);
}

extern "C" void kernel_launch(void* const* d_in, const int* in_sizes, int n_in,
                              void* d_out, int out_size, void* d_ws, size_t ws_size,
                              hipStream_t stream)
{
    const float* I0 = (const float*)d_in[0];
    const float* J0 = (const float*)d_in[1];
    float* out = (float*)d_out;

    char* ws = (char*)d_ws;
    double* acc = (double*)ws;                         // 3 doubles
    float* I1 = (float*)(ws + 256);
    float* J1 = I1 + (size_t)2 * 80 * 96 * 80;
    float* I2 = J1 + (size_t)2 * 80 * 96 * 80;
    float* J2 = I2 + (size_t)2 * 40 * 48 * 40;

    hipMemsetAsync(acc, 0, 3 * sizeof(double), stream);

    // ---- scale 0: 160x192x160, win=9 ----
    {
        int H = 192, W = 160, D = 160;
        int tilesH = 12, tilesW = 10;
        int chunksD = 6, chunkLen = 27;                 // 1440 blocks = 5.6/CU
        int blocks = 2 * tilesH * tilesW * chunksD;
        ncc_scale_kernel<9><<<blocks, 256, 0, stream>>>(I0, J0, D, H, W,
                                                        tilesH, tilesW, chunksD, chunkLen,
                                                        acc + 0);
    }
    // ---- pool level 0 -> 1 (I and J in one launch) ----
    {
        int total = 2 * 80 * 96 * 80;
        int blocks = (2 * total + 255) / 256;
        pool_kernel2<<<blocks, 256, 0, stream>>>(I0, J0, I1, J1,
                                                 160, 192, 160, 80, 96, 80, total);
    }
    // ---- scale 1: 80x96x80, win=7 ----
    {
        int H = 96, W = 80, D = 80;
        int tilesH = 6, tilesW = 5;
        int chunksD = 10, chunkLen = 8;                 // 600 blocks
        int blocks = 2 * tilesH * tilesW * chunksD;
        ncc_scale_kernel<7><<<blocks, 256, 0, stream>>>(I1, J1, D, H, W,
                                                        tilesH, tilesW, chunksD, chunkLen,
                                                        acc + 1);
    }
    // ---- pool level 1 -> 2 ----
    {
        int total = 2 * 40 * 48 * 40;
        int blocks = (2 * total + 255) / 256;
        pool_kernel2<<<blocks, 256, 0, stream>>>(I1, J1, I2, J2,
                                                 80, 96, 80, 40, 48, 40, total);
    }
    // ---- scale 2: 40x48x40, win=5 ----
    {
        int H = 48, W = 40, D = 40;
        int tilesH = 3, tilesW = 3;
        int chunksD = 10, chunkLen = 4;                 // 180 blocks
        int blocks = 2 * tilesH * tilesW * chunksD;
        ncc_scale_kernel<5><<<blocks, 256, 0, stream>>>(I2, J2, D, H, W,
                                                        tilesH, tilesW, chunksD, chunkLen,
                                                        acc + 2);
    }

    finalize_kernel<<<1, 1, 0, stream>>>(acc, out);
}

// Round 5
// 228.026 us; speedup vs baseline: 1.1564x; 1.0307x over previous
//
#include <hip/hip_runtime.h>

#define NCC_EPS 1.1920929e-07f

// ---------------------------------------------------------------------------
// Fused single-scale NCC: per block = one 16x16 (H,W) tile x one D-chunk.
// March along D keeping a WIN-deep register ring of HW-box-filtered slices
// (5 channels: I, J, I^2, J^2, I*J) and running D-window sums.
//
// W-filter is computed IN REGISTERS from global memory (no LDS staging):
//   thread (r, c4) loads 12 floats (3 aligned float4) per array covering
//   out-cols [4c4, 4c4+4) + halo, does 5-channel sliding window sums in
//   VALU, writes once to LDS. L1 serves the 3x overlap between neighbors.
// LDS holds only the W-filtered slice (double-buffered -> 1 barrier/slice):
//   wb0123: float4/col, row stride 68 (quad (r+ww)%8 uniform -> 8 words/bank
//           = b128 floor, conflict-free for both write and H-read patterns)
//   wb4:    scalar, row stride 24 (max 2-way on reads = free; float4 writes
//           uniform)
// H-pass: 9 taps x (1 b128 + 1 b32) per point.
// ---------------------------------------------------------------------------
template<int WIN>
__global__ __launch_bounds__(256)
void ncc_scale_kernel(const float* __restrict__ I, const float* __restrict__ J,
                      int D, int H, int W,
                      int tilesH, int tilesW, int chunksD, int chunkLen,
                      double* __restrict__ acc)
{
    constexpr int RAD  = WIN / 2;
    constexpr int TH = 16, TW = 16;
    constexpr int WROWS = TH + 2 * RAD;   // wb rows (H extent incl. halo)
    constexpr int PSTR = 68;              // wb0123 row stride: 16*4 + 4 pad
    constexpr int QSTR = 24;              // wb4 row stride
    constexpr int OFF  = 4 - RAD;         // window start inside 12-float regs
    constexpr int NWT  = WROWS * 4;       // active W-phase threads
    constexpr float invV = 1.0f / (float)(WIN * WIN * WIN);

    __shared__ __align__(16) float wb0123[2][WROWS * PSTR];
    __shared__ __align__(16) float wb4[2][WROWS * QSTR];
    __shared__ float red[4];

    int bid = blockIdx.x;
    int tw = bid % tilesW; bid /= tilesW;
    int th = bid % tilesH; bid /= tilesH;
    int cd = bid % chunksD; bid /= chunksD;
    int b  = bid;

    const int h0 = th * TH, w0 = tw * TW;
    const int z0 = cd * chunkLen;
    const int z1 = min(z0 + chunkLen, D);

    const size_t plane = (size_t)H * W;
    const float* Ib = I + (size_t)b * D * plane;
    const float* Jb = J + (size_t)b * D * plane;

    const int t  = threadIdx.x;
    const int hh = t >> 4, ww = t & 15;       // owned output point in tile
    const int gh = h0 + hh, gw = w0 + ww;
    const bool valid = (gh < H) && (gw < W);

    // W-phase mapping: wb row wr, col group wc4 (4 out-cols per thread)
    const int wr  = t >> 2;
    const int wc4 = t & 3;
    const bool wact = t < NWT;
    const int wbase = w0 + 4 * wc4 - 4;       // global col of regs[0] (4-aligned)
    const int wghr  = h0 + wr - RAD;          // global row this thread filters

    float ring[WIN][5];
    float rs[5];
    #pragma unroll
    for (int s = 0; s < WIN; ++s)
        #pragma unroll
        for (int c = 0; c < 5; ++c) ring[s][c] = 0.f;
    #pragma unroll
    for (int c = 0; c < 5; ++c) rs[c] = 0.f;

    float ccsum = 0.f;

    const int zend = z1 + RAD;
    for (int zb = z0 - RAD; zb < zend; zb += WIN) {
        #pragma unroll
        for (int ph = 0; ph < WIN; ++ph) {
            const int z = zb + ph;                 // uniform across block
            if (z < zend) {
                const bool zin = (z >= 0) && (z < D);   // uniform
                float n0 = 0, n1 = 0, n2 = 0, n3 = 0, n4 = 0;
                if (zin) {
                    const int par = (z + 64) & 1;       // uniform buffer parity
                    // ---- W phase: global->reg, sliding sums, LDS write ----
                    if (wact) {
                        float fi[12], fj[12];
                        if (wghr >= 0 && wghr < H) {
                            const float* rowI = Ib + (size_t)z * plane + (size_t)wghr * W;
                            const float* rowJ = Jb + (size_t)z * plane + (size_t)wghr * W;
                            if (wbase >= 0 && wbase + 12 <= W) {
                                float4 a0 = *reinterpret_cast<const float4*>(rowI + wbase);
                                float4 a1 = *reinterpret_cast<const float4*>(rowI + wbase + 4);
                                float4 a2 = *reinterpret_cast<const float4*>(rowI + wbase + 8);
                                float4 b0 = *reinterpret_cast<const float4*>(rowJ + wbase);
                                float4 b1 = *reinterpret_cast<const float4*>(rowJ + wbase + 4);
                                float4 b2 = *reinterpret_cast<const float4*>(rowJ + wbase + 8);
                                fi[0]=a0.x; fi[1]=a0.y; fi[2]=a0.z; fi[3]=a0.w;
                                fi[4]=a1.x; fi[5]=a1.y; fi[6]=a1.z; fi[7]=a1.w;
                                fi[8]=a2.x; fi[9]=a2.y; fi[10]=a2.z; fi[11]=a2.w;
                                fj[0]=b0.x; fj[1]=b0.y; fj[2]=b0.z; fj[3]=b0.w;
                                fj[4]=b1.x; fj[5]=b1.y; fj[6]=b1.z; fj[7]=b1.w;
                                fj[8]=b2.x; fj[9]=b2.y; fj[10]=b2.z; fj[11]=b2.w;
                            } else {
                                #pragma unroll
                                for (int e = 0; e < 12; ++e) {
                                    int cg = wbase + e;
                                    bool ok = (cg >= 0) && (cg < W);
                                    fi[e] = ok ? rowI[cg] : 0.f;
                                    fj[e] = ok ? rowJ[cg] : 0.f;
                                }
                            }
                        } else {
                            #pragma unroll
                            for (int e = 0; e < 12; ++e) { fi[e] = 0.f; fj[e] = 0.f; }
                        }
                        // sliding 5-channel window sums over 4 output cols
                        float s0 = 0, s1 = 0, s2 = 0, s3 = 0, s4 = 0;
                        #pragma unroll
                        for (int k = 0; k < WIN; ++k) {
                            float a = fi[OFF + k], bb = fj[OFF + k];
                            s0 += a; s1 += bb;
                            s2 = fmaf(a, a, s2);
                            s3 = fmaf(bb, bb, s3);
                            s4 = fmaf(a, bb, s4);
                        }
                        float o0[4], o1[4], o2[4], o3[4], o4[4];
                        o0[0]=s0; o1[0]=s1; o2[0]=s2; o3[0]=s3; o4[0]=s4;
                        #pragma unroll
                        for (int m = 1; m < 4; ++m) {
                            float aL = fi[OFF + m - 1],       bL = fj[OFF + m - 1];
                            float aR = fi[OFF + m - 1 + WIN], bR = fj[OFF + m - 1 + WIN];
                            s0 += aR - aL;
                            s1 += bR - bL;
                            s2 = s2 + aR * aR - aL * aL;
                            s3 = s3 + bR * bR - bL * bL;
                            s4 = s4 + aR * bR - aL * bL;
                            o0[m]=s0; o1[m]=s1; o2[m]=s2; o3[m]=s3; o4[m]=s4;
                        }
                        #pragma unroll
                        for (int m = 0; m < 4; ++m) {
                            *reinterpret_cast<float4*>(&wb0123[par][wr * PSTR + 16 * wc4 + 4 * m]) =
                                make_float4(o0[m], o1[m], o2[m], o3[m]);
                        }
                        *reinterpret_cast<float4*>(&wb4[par][wr * QSTR + 4 * wc4]) =
                            make_float4(o4[0], o4[1], o4[2], o4[3]);
                    }
                    __syncthreads();
                    // ---- H phase: 9 taps of (b128 + b32) ----
                    float4 a4 = make_float4(0.f, 0.f, 0.f, 0.f);
                    #pragma unroll
                    for (int dh = 0; dh < WIN; ++dh) {
                        float4 v = *reinterpret_cast<const float4*>(
                            &wb0123[par][(hh + dh) * PSTR + 4 * ww]);
                        a4.x += v.x; a4.y += v.y; a4.z += v.z; a4.w += v.w;
                        n4 += wb4[par][(hh + dh) * QSTR + ww];
                    }
                    n0 = a4.x; n1 = a4.y; n2 = a4.z; n3 = a4.w;
                }
                // ---- ring update (zeros for out-of-range slices) ----
                rs[0] += n0 - ring[ph][0]; ring[ph][0] = n0;
                rs[1] += n1 - ring[ph][1]; ring[ph][1] = n1;
                rs[2] += n2 - ring[ph][2]; ring[ph][2] = n2;
                rs[3] += n3 - ring[ph][3]; ring[ph][3] = n3;
                rs[4] += n4 - ring[ph][4]; ring[ph][4] = n4;

                // ---- emit cc for output slice zo = z - RAD ----
                const int zo = z - RAD;
                if (valid && zo >= z0) {
                    float muI = rs[0] * invV;
                    float muJ = rs[1] * invV;
                    float sII = rs[2] * invV - muI * muI;
                    float sJJ = rs[3] * invV - muJ * muJ;
                    float s12 = rs[4] * invV - muI * muJ;
                    float cc = (s12 * s12) / fmaxf(sII * sJJ, NCC_EPS);
                    ccsum += cc;
                }
            }
        }
    }

    // ---- block reduction -> global double accumulator ----
    for (int off = 32; off > 0; off >>= 1)
        ccsum += __shfl_down(ccsum, off);
    const int wid = t >> 6, lane = t & 63;
    if (lane == 0) red[wid] = ccsum;
    __syncthreads();
    if (t == 0) {
        float s = red[0] + red[1] + red[2] + red[3];
        atomicAdd(acc, (double)s);
    }
}

// ---------------------------------------------------------------------------
// avg_pool3d, k=3, stride=2, pad=1, count_include_pad=False.
// One launch handles both I and J (idx >= total -> J).
// ---------------------------------------------------------------------------
__global__ void pool_kernel2(const float* __restrict__ inA, const float* __restrict__ inB,
                             float* __restrict__ outA, float* __restrict__ outB,
                             int D, int H, int W, int oD, int oH, int oW, int total)
{
    int idx0 = blockIdx.x * 256 + threadIdx.x;
    if (idx0 >= 2 * total) return;
    const bool isB = idx0 >= total;
    int idx = isB ? idx0 - total : idx0;
    const float* in = isB ? inB : inA;
    float* out = isB ? outB : outA;

    int ow = idx % oW; int tmp = idx / oW;
    int oh = tmp % oH; tmp /= oH;
    int od = tmp % oD; int b = tmp / oD;

    int d0 = 2 * od - 1, h0 = 2 * oh - 1, w0 = 2 * ow - 1;
    int dlo = max(d0, 0), dhi = min(d0 + 3, D);
    int hlo = max(h0, 0), hhi = min(h0 + 3, H);
    int wlo = max(w0, 0), whi = min(w0 + 3, W);

    const float* ib = in + (size_t)b * D * H * W;
    float s = 0.f;
    for (int d = dlo; d < dhi; ++d)
        for (int h = hlo; h < hhi; ++h)
            for (int w = wlo; w < whi; ++w)
                s += ib[((size_t)d * H + h) * W + w];
    int cnt = (dhi - dlo) * (hhi - hlo) * (whi - wlo);
    out[idx] = s / (float)cnt;
}

__global__ void finalize_kernel(const double* __restrict__ acc, float* __restrict__ out)
{
    double m = acc[0] / 9830400.0 + acc[1] / 1228800.0 + acc[2] / 153600.0;
    out[0] = (float)(-m / 3.0);
}

extern "C" void kernel_launch(void* const* d_in, const int* in_sizes, int n_in,
                              void* d_out, int out_size, void* d_ws, size_t ws_size,
                              hipStream_t stream)
{
    const float* I0 = (const float*)d_in[0];
    const float* J0 = (const float*)d_in[1];
    float* out = (float*)d_out;

    char* ws = (char*)d_ws;
    double* acc = (double*)ws;                         // 3 doubles
    float* I1 = (float*)(ws + 256);
    float* J1 = I1 + (size_t)2 * 80 * 96 * 80;
    float* I2 = J1 + (size_t)2 * 80 * 96 * 80;
    float* J2 = I2 + (size_t)2 * 40 * 48 * 40;

    hipMemsetAsync(acc, 0, 3 * sizeof(double), stream);

    // ---- scale 0: 160x192x160, win=9 ----
    {
        int H = 192, W = 160, D = 160;
        int tilesH = 12, tilesW = 10;
        int chunksD = 5, chunkLen = 32;                 // 1200 blocks = 4.7/CU
        int blocks = 2 * tilesH * tilesW * chunksD;
        ncc_scale_kernel<9><<<blocks, 256, 0, stream>>>(I0, J0, D, H, W,
                                                        tilesH, tilesW, chunksD, chunkLen,
                                                        acc + 0);
    }
    // ---- pool level 0 -> 1 (I and J in one launch) ----
    {
        int total = 2 * 80 * 96 * 80;
        int blocks = (2 * total + 255) / 256;
        pool_kernel2<<<blocks, 256, 0, stream>>>(I0, J0, I1, J1,
                                                 160, 192, 160, 80, 96, 80, total);
    }
    // ---- scale 1: 80x96x80, win=7 ----
    {
        int H = 96, W = 80, D = 80;
        int tilesH = 6, tilesW = 5;
        int chunksD = 8, chunkLen = 10;                 // 480 blocks
        int blocks = 2 * tilesH * tilesW * chunksD;
        ncc_scale_kernel<7><<<blocks, 256, 0, stream>>>(I1, J1, D, H, W,
                                                        tilesH, tilesW, chunksD, chunkLen,
                                                        acc + 1);
    }
    // ---- pool level 1 -> 2 ----
    {
        int total = 2 * 40 * 48 * 40;
        int blocks = (2 * total + 255) / 256;
        pool_kernel2<<<blocks, 256, 0, stream>>>(I1, J1, I2, J2,
                                                 80, 96, 80, 40, 48, 40, total);
    }
    // ---- scale 2: 40x48x40, win=5 ----
    {
        int H = 48, W = 40, D = 40;
        int tilesH = 3, tilesW = 3;
        int chunksD = 10, chunkLen = 4;                 // 180 blocks
        int blocks = 2 * tilesH * tilesW * chunksD;
        ncc_scale_kernel<5><<<blocks, 256, 0, stream>>>(I2, J2, D, H, W,
                                                        tilesH, tilesW, chunksD, chunkLen,
                                                        acc + 2);
    }

    finalize_kernel<<<1, 1, 0, stream>>>(acc, out);
}